// Round 8
// baseline (284.428 us; speedup 1.0000x reference)
//
#include <hip/hip_runtime.h>

#define NN 50000
#define EE 800000
#define DD 64
#define BN_EPS 1e-5f

#define NPART 8
#define PART_NODES 6250        // 50000/8
#define CAP 64                 // padded CSR slots per node (P(deg>64) ~ 1e-20)
#define BCAP 131072            // bucket capacity per partition (expect ~100K)
#define NSCAT 32               // scatter blocks per partition
#define NB_BUCKET 782          // ceil(800000/1024)
#define NB_AGG  12500          // 4 nodes (waves) per block
#define NB_ROW  196            // 1 thread/row for mlp
#define NB_ELT8 1563           // ceil(50000*8/256) threads, 8 elems each
#define NB_APPLY 3125          // 50000*16 float4 / 256

__global__ void k_zero_i32(int* __restrict__ p, int n) {
    int i = blockIdx.x * blockDim.x + threadIdx.x;
    if (i < n) p[i] = 0;
}

__global__ void k_zero_f32(float* __restrict__ p, int n) {
    int i = blockIdx.x * blockDim.x + threadIdx.x;
    if (i < n) p[i] = 0.f;
}

// round-to-nearest-even f32 -> bf16, packed pair into u32 (lo = even elem)
__device__ __forceinline__ unsigned bfpack2(float a, float b) {
    union { float f; unsigned u; } ua, ub;
    ua.f = a; ub.f = b;
    unsigned ra = ua.u + 0x7fffu + ((ua.u >> 16) & 1u);
    unsigned rb = ub.u + 0x7fffu + ((ub.u >> 16) & 1u);
    return (ra >> 16) | (rb & 0xffff0000u);
}

// ---- CSR build phase A: bucket edges by dst partition (read each edge ONCE).
// bucketCnt[p*16] spreads the 8 counters across 8 cache lines.
__global__ __launch_bounds__(1024) void k_bucket(const int* __restrict__ src,
                                                 const int* __restrict__ dst,
                                                 unsigned long long* __restrict__ bucket,
                                                 int* __restrict__ bucketCnt) {
    __shared__ int lcnt[8];
    __shared__ int lbase[8];
    int t = threadIdx.x;
    if (t < 8) lcnt[t] = 0;
    __syncthreads();
    int e = blockIdx.x * 1024 + t;
    int d = 0, s = 0, p = 0, loc = 0;
    bool ok = (e < EE);
    if (ok) {
        d = __builtin_nontemporal_load(dst + e);
        s = __builtin_nontemporal_load(src + e);
        p = (unsigned)d / PART_NODES;
        loc = atomicAdd(&lcnt[p], 1);
    }
    __syncthreads();
    if (t < 8) lbase[t] = atomicAdd(&bucketCnt[t * 16], lcnt[t]);
    __syncthreads();
    if (ok) {
        unsigned long long v = ((unsigned long long)(unsigned)s << 32) | (unsigned)d;
        bucket[(size_t)p * BCAP + lbase[p] + loc] = v;
    }
}

// ---- CSR build phase B: scatter bucket p into col slice p (XCD-local dirty
// lines: all blocks with blockIdx&7==p land on XCD p under round-robin).
// cursor doubles as the degree array afterwards.
__global__ __launch_bounds__(256) void k_scatter(const unsigned long long* __restrict__ bucket,
                                                 const int* __restrict__ bucketCnt,
                                                 int* __restrict__ cursor,
                                                 int* __restrict__ col) {
    int p = blockIdx.x & 7;
    int cnt = bucketCnt[p * 16];
    const unsigned long long* b = bucket + (size_t)p * BCAP;
    for (int i = (blockIdx.x >> 3) * 256 + threadIdx.x; i < cnt; i += NSCAT * 8 * 32) {
        unsigned long long v = __builtin_nontemporal_load(b + i);
        int d = (int)(v & 0xffffffffu);
        int s = (int)(v >> 32);
        int pos = atomicAdd(&cursor[d], 1);
        col[d * CAP + pos] = s;
    }
}

// x (f32) -> bf16 packed, 8 elems per thread
__global__ __launch_bounds__(256) void k_cvt(const float* __restrict__ x,
                                             unsigned* __restrict__ xb) {
    int t = blockIdx.x * 256 + threadIdx.x;
    if (t >= NN * 8) return;
    const float4* p = (const float4*)(x + (size_t)t * 8);
    float4 a = p[0], b = p[1];
    uint4 o;
    o.x = bfpack2(a.x, a.y); o.y = bfpack2(a.z, a.w);
    o.z = bfpack2(b.x, b.y); o.w = bfpack2(b.z, b.w);
    ((uint4*)xb)[t] = o;
}

// BN affine + ReLU + f32->bf16 pack, 8 elems per thread
__global__ __launch_bounds__(256) void k_bnapply16(const float* __restrict__ Z,
                                                   const float* __restrict__ bnA,
                                                   const float* __restrict__ bnC,
                                                   unsigned* __restrict__ hb) {
    __shared__ float sa[64];
    __shared__ float sc[64];
    int tt = threadIdx.x;
    if (tt < 64) { sa[tt] = bnA[tt]; sc[tt] = bnC[tt]; }
    __syncthreads();
    int t = blockIdx.x * 256 + tt;
    if (t >= NN * 8) return;
    int cb = (t & 7) * 8;
    const float4* p = (const float4*)(Z + (size_t)t * 8);
    float4 a = p[0], b = p[1];
    a.x = fmaxf(fmaf(a.x, sa[cb + 0], sc[cb + 0]), 0.f);
    a.y = fmaxf(fmaf(a.y, sa[cb + 1], sc[cb + 1]), 0.f);
    a.z = fmaxf(fmaf(a.z, sa[cb + 2], sc[cb + 2]), 0.f);
    a.w = fmaxf(fmaf(a.w, sa[cb + 3], sc[cb + 3]), 0.f);
    b.x = fmaxf(fmaf(b.x, sa[cb + 4], sc[cb + 4]), 0.f);
    b.y = fmaxf(fmaf(b.y, sa[cb + 5], sc[cb + 5]), 0.f);
    b.z = fmaxf(fmaf(b.z, sa[cb + 6], sc[cb + 6]), 0.f);
    b.w = fmaxf(fmaf(b.w, sa[cb + 7], sc[cb + 7]), 0.f);
    uint4 o;
    o.x = bfpack2(a.x, a.y); o.y = bfpack2(a.z, a.w);
    o.z = bfpack2(b.x, b.y); o.w = bfpack2(b.z, b.w);
    ((uint4*)hb)[t] = o;
}

// z[i,:] = h[i,:] + sum_{j in N(i)} h[j,:]  from bf16 rows (128B = 2 lines).
// Wave per node: lane = slot*8 + li; 8 slots x unroll-2 = 16 rows in flight.
__global__ __launch_bounds__(256) void k_agg4(const unsigned* __restrict__ hb,
                                              const int* __restrict__ deg,
                                              const int* __restrict__ col,
                                              float* __restrict__ outB) {
    int node = blockIdx.x * 4 + (threadIdx.x >> 6);   // grid exact: 12500*4
    int lane = threadIdx.x & 63;
    int li = lane & 7;
    int slot = lane >> 3;
    int dn = deg[node];
    int base = node * CAP;
    const uint4* hb4 = (const uint4*)hb;
    float acc[8];
#pragma unroll
    for (int i = 0; i < 8; ++i) acc[i] = 0.f;

#define UNPK_ADD(U)                                                      \
    {                                                                    \
        uint4 _u = (U);                                                  \
        union { unsigned u; float f; } l0, h0, l1, h1, l2, h2, l3, h3;   \
        l0.u = _u.x << 16; h0.u = _u.x & 0xffff0000u;                    \
        l1.u = _u.y << 16; h1.u = _u.y & 0xffff0000u;                    \
        l2.u = _u.z << 16; h2.u = _u.z & 0xffff0000u;                    \
        l3.u = _u.w << 16; h3.u = _u.w & 0xffff0000u;                    \
        acc[0] += l0.f; acc[1] += h0.f; acc[2] += l1.f; acc[3] += h1.f;  \
        acc[4] += l2.f; acc[5] += h2.f; acc[6] += l3.f; acc[7] += h3.f;  \
    }

    // self row via slot 0 (independent of the neighbor chain)
    if (slot == 0)
        UNPK_ADD(hb4[(size_t)node * 8 + li]);

    int k = slot;
    for (; k + 8 < dn; k += 16) {      // two rows in flight per slot
        int s0 = __builtin_nontemporal_load(col + base + k);
        int s1 = __builtin_nontemporal_load(col + base + k + 8);
        uint4 u0 = hb4[(size_t)s0 * 8 + li];
        uint4 u1 = hb4[(size_t)s1 * 8 + li];
        UNPK_ADD(u0);
        UNPK_ADD(u1);
    }
    if (k < dn) {
        int s0 = __builtin_nontemporal_load(col + base + k);
        UNPK_ADD(hb4[(size_t)s0 * 8 + li]);
    }
#undef UNPK_ADD

#pragma unroll
    for (int i = 0; i < 8; ++i) acc[i] += __shfl_xor(acc[i], 8);
#pragma unroll
    for (int i = 0; i < 8; ++i) acc[i] += __shfl_xor(acc[i], 16);
#pragma unroll
    for (int i = 0; i < 8; ++i) acc[i] += __shfl_xor(acc[i], 32);

    if (slot == 0) {
        float4 o0 = make_float4(acc[0], acc[1], acc[2], acc[3]);
        float4 o1 = make_float4(acc[4], acc[5], acc[6], acc[7]);
        float4* orow = (float4*)(outB + (size_t)node * 64 + li * 8);
        orow[0] = o0;
        orow[1] = o1;
    }
}

// fused MLP: B = relu(B@W1+b1)@W2+b2   (in place, one row per thread)
__global__ __launch_bounds__(256) void k_mlp(float* __restrict__ B,
                                             const float* __restrict__ W1,
                                             const float* __restrict__ b1,
                                             const float* __restrict__ W2,
                                             const float* __restrict__ b2) {
    __shared__ float w1s[4096];
    __shared__ float w2s[4096];
    __shared__ float b1s[64];
    __shared__ float b2s[64];
    int t = threadIdx.x;
    for (int i = t; i < 4096; i += 256) {
        w1s[i] = W1[i];
        w2s[i] = W2[i];
    }
    if (t < 64) { b1s[t] = b1[t]; b2s[t] = b2[t]; }
    __syncthreads();

    int row = blockIdx.x * 256 + t;
    if (row >= NN) return;

    const float4* xr = (const float4*)(B + (size_t)row * 64);
    float z1[64];
#pragma unroll
    for (int j = 0; j < 64; ++j) z1[j] = b1s[j];

    for (int k4 = 0; k4 < 16; ++k4) {
        float4 xv = xr[k4];
        float xs[4] = {xv.x, xv.y, xv.z, xv.w};
#pragma unroll
        for (int kk = 0; kk < 4; ++kk) {
            float xk = xs[kk];
            const float* wr = &w1s[(k4 * 4 + kk) * 64];
#pragma unroll
            for (int j = 0; j < 64; ++j) z1[j] = fmaf(xk, wr[j], z1[j]);
        }
    }
#pragma unroll
    for (int j = 0; j < 64; ++j) z1[j] = fmaxf(z1[j], 0.f);

    float4* orow = (float4*)(B + (size_t)row * 64);
    for (int j4 = 0; j4 < 16; ++j4) {
        float4 o = make_float4(b2s[j4 * 4 + 0], b2s[j4 * 4 + 1],
                               b2s[j4 * 4 + 2], b2s[j4 * 4 + 3]);
#pragma unroll
        for (int k = 0; k < 64; ++k) {
            float4 w = *(const float4*)&w2s[k * 64 + j4 * 4];
            o.x = fmaf(z1[k], w.x, o.x);
            o.y = fmaf(z1[k], w.y, o.y);
            o.z = fmaf(z1[k], w.z, o.z);
            o.w = fmaf(z1[k], w.w, o.w);
        }
        orow[j4] = o;
    }
}

// per-column sum & sumsq -> stats[0:64]=sum, stats[64:128]=sumsq
__global__ __launch_bounds__(256) void k_stats(const float* __restrict__ B,
                                               float* __restrict__ stats) {
    __shared__ float ssum[256];
    __shared__ float sss[256];
    int t = threadIdx.x;
    int g = blockIdx.x * 256 + t;
    int c = g & 63;
    int rs = g >> 6;
    int stride = (gridDim.x * 256) >> 6;
    float sum = 0.f, ss = 0.f;
    for (int r = rs; r < NN; r += stride) {
        float v = B[(size_t)r * 64 + c];
        sum += v;
        ss = fmaf(v, v, ss);
    }
    ssum[t] = sum;
    sss[t] = ss;
    __syncthreads();
    if (t < 64) {
        float s4 = ssum[t] + ssum[t + 64] + ssum[t + 128] + ssum[t + 192];
        float q4 = sss[t] + sss[t + 64] + sss[t + 128] + sss[t + 192];
        atomicAdd(&stats[t], s4);
        atomicAdd(&stats[64 + t], q4);
    }
}

// stats -> per-column affine (a = gamma*istd, c = beta - mean*a); re-zero stats
__global__ void k_bnparam(float* __restrict__ stats,
                          const float* __restrict__ gamma,
                          const float* __restrict__ beta,
                          float* __restrict__ bnA, float* __restrict__ bnC) {
    int t = threadIdx.x;   // 64
    float mean = stats[t] * (1.f / NN);
    float var = stats[64 + t] * (1.f / NN) - mean * mean;
    float a = gamma[t] * rsqrtf(var + BN_EPS);
    bnA[t] = a;
    bnC[t] = fmaf(-mean, a, beta[t]);
    stats[t] = 0.f;
    stats[64 + t] = 0.f;
}

// final BN apply (affine form, no relu, f32 out)
__global__ __launch_bounds__(256) void k_apply_aff(const float* __restrict__ B,
                                                   const float* __restrict__ bnA,
                                                   const float* __restrict__ bnC,
                                                   float* __restrict__ out) {
    __shared__ float sa[64];
    __shared__ float sc[64];
    int t = threadIdx.x;
    if (t < 64) { sa[t] = bnA[t]; sc[t] = bnC[t]; }
    __syncthreads();
    int i4 = blockIdx.x * 256 + t;
    if (i4 >= NN * 16) return;
    int cb = (i4 & 15) * 4;
    float4 v = ((const float4*)B)[i4];
    float4 o;
    o.x = fmaf(v.x, sa[cb + 0], sc[cb + 0]);
    o.y = fmaf(v.y, sa[cb + 1], sc[cb + 1]);
    o.z = fmaf(v.z, sa[cb + 2], sc[cb + 2]);
    o.w = fmaf(v.w, sa[cb + 3], sc[cb + 3]);
    ((float4*)out)[i4] = o;
}

extern "C" void kernel_launch(void* const* d_in, const int* in_sizes, int n_in,
                              void* d_out, int out_size, void* d_ws, size_t ws_size,
                              hipStream_t stream) {
    const float* x     = (const float*)d_in[0];
    const int*   ei    = (const int*)d_in[1];   // [2][E]
    const float* W1    = (const float*)d_in[2];
    const float* b1    = (const float*)d_in[3];
    const float* W2    = (const float*)d_in[4];
    const float* b2    = (const float*)d_in[5];
    const float* gamma = (const float*)d_in[6];
    const float* beta  = (const float*)d_in[7];
    float* out = (float*)d_out;

    const int* src = ei;        // edge_index[0]
    const int* dst = ei + EE;   // edge_index[1]

    char* w = (char*)d_ws;
    float*    Z0    = (float*)w;    w += (size_t)NN * DD * 4;       // 12.8 MB
    float*    Z1    = (float*)w;    w += (size_t)NN * DD * 4;       // 12.8 MB
    unsigned* Hb    = (unsigned*)w; w += (size_t)NN * DD * 2;       // 6.4 MB bf16
    unsigned* Xb    = (unsigned*)w; w += (size_t)NN * DD * 2;       // 6.4 MB bf16
    int*      col   = (int*)w;      w += (size_t)NN * CAP * 4;      // 12.8 MB padded CSR
    unsigned long long* bucket = (unsigned long long*)w;
    w += (size_t)NPART * BCAP * 8;                                  // 8.4 MB
    int*      cursor= (int*)w;      w += (size_t)NN * 4;            // degree after fill
    int*      bucketCnt = (int*)w;  w += 128 * 4;                   // 8 counters, stride 16
    float*    stats = (float*)w;    w += 128 * 4;
    float*    bnA   = (float*)w;    w += 64 * 4;
    float*    bnC   = (float*)w;    w += 64 * 4;

    // ---- CSR build: zero, bucket (1 pass over edges), scatter ----
    k_zero_i32<<<197, 256, 0, stream>>>(cursor, NN + 128);  // cursor + bucketCnt adjacent
    k_zero_f32<<<1, 128, 0, stream>>>(stats, 128);
    k_bucket<<<NB_BUCKET, 1024, 0, stream>>>(src, dst, bucket, bucketCnt);
    k_cvt<<<NB_ELT8, 256, 0, stream>>>(x, Xb);              // independent, hides between
    k_scatter<<<NPART * NSCAT, 256, 0, stream>>>(bucket, bucketCnt, cursor, col);

    // ---- layer 0 ----
    k_agg4<<<NB_AGG, 256, 0, stream>>>(Xb, cursor, col, Z0);
    k_mlp<<<NB_ROW, 256, 0, stream>>>(Z0, W1, b1, W2, b2);
    k_stats<<<256, 256, 0, stream>>>(Z0, stats);
    k_bnparam<<<1, 64, 0, stream>>>(stats, gamma, beta, bnA, bnC);
    k_bnapply16<<<NB_ELT8, 256, 0, stream>>>(Z0, bnA, bnC, Hb);

    // ---- layer 1 ----
    k_agg4<<<NB_AGG, 256, 0, stream>>>(Hb, cursor, col, Z1);
    k_mlp<<<NB_ROW, 256, 0, stream>>>(Z1, W1 + 4096, b1 + 64, W2 + 4096, b2 + 64);
    k_stats<<<256, 256, 0, stream>>>(Z1, stats);
    k_bnparam<<<1, 64, 0, stream>>>(stats, gamma + 64, beta + 64, bnA, bnC);
    k_bnapply16<<<NB_ELT8, 256, 0, stream>>>(Z1, bnA, bnC, Hb);

    // ---- layer 2 ----
    k_agg4<<<NB_AGG, 256, 0, stream>>>(Hb, cursor, col, Z0);
    k_mlp<<<NB_ROW, 256, 0, stream>>>(Z0, W1 + 8192, b1 + 128, W2 + 8192, b2 + 128);
    k_stats<<<256, 256, 0, stream>>>(Z0, stats);
    k_bnparam<<<1, 64, 0, stream>>>(stats, gamma + 128, beta + 128, bnA, bnC);
    k_apply_aff<<<NB_APPLY, 256, 0, stream>>>(Z0, bnA, bnC, out);
}

// Round 9
// 245.235 us; speedup vs baseline: 1.1598x; 1.1598x over previous
//
#include <hip/hip_runtime.h>

#define NN 50000
#define EE 800000
#define DD 64
#define BN_EPS 1e-5f

#define NPART 8
#define PART_NODES 6250        // 50000/8
#define CAP 64                 // padded CSR slots per node
#define BCAP 131072            // bucket capacity per partition (expect ~100K)
#define NSCAT 32               // scatter blocks per partition
#define NB_BUCKET 782          // ceil(800000/1024)
#define NB_AGG  12500          // 4 nodes (waves) per block
#define NB_MLP  782            // 64 rows per block (4 waves x 16)
#define NB_ELT8 1563           // ceil(50000*8/256)
#define NB_APPLY 3125          // 50000*16 float4 / 256

typedef __attribute__((ext_vector_type(8))) short short8v;   // 8 bf16 = 4 VGPR
typedef __attribute__((ext_vector_type(4))) float float4v;   // MFMA acc

__device__ __forceinline__ unsigned bfpack2(float a, float b) {
    union { float f; unsigned u; } ua, ub;
    ua.f = a; ub.f = b;
    unsigned ra = ua.u + 0x7fffu + ((ua.u >> 16) & 1u);
    unsigned rb = ub.u + 0x7fffu + ((ub.u >> 16) & 1u);
    return (ra >> 16) | (rb & 0xffff0000u);
}

__device__ __forceinline__ unsigned short bf16of(float v) {
    union { float f; unsigned u; } x; x.f = v;
    unsigned r = x.u + 0x7fffu + ((x.u >> 16) & 1u);
    return (unsigned short)(r >> 16);
}

// zero the small control buffers once (bucketCnt[128] + stats[384])
__global__ void k_zero_small(int* __restrict__ bucketCnt, float* __restrict__ stats) {
    int t = threadIdx.x;
    if (t < 128) bucketCnt[t] = 0;
    if (t < 384) stats[t] = 0.f;
}

// phase A: bucket edges by dst partition (one pass over edges) + zero cursor
__global__ __launch_bounds__(1024) void k_build(const int* __restrict__ src,
                                                const int* __restrict__ dst,
                                                unsigned long long* __restrict__ bucket,
                                                int* __restrict__ bucketCnt,
                                                int* __restrict__ cursor) {
    __shared__ int lcnt[8];
    __shared__ int lbase[8];
    int t = threadIdx.x;
    int g = blockIdx.x * 1024 + t;
    if (g < NN) cursor[g] = 0;           // used only by k_scatter (next kernel)
    if (t < 8) lcnt[t] = 0;
    __syncthreads();
    int d = 0, s = 0, p = 0, loc = 0;
    bool ok = (g < EE);
    if (ok) {
        d = __builtin_nontemporal_load(dst + g);
        s = __builtin_nontemporal_load(src + g);
        p = (unsigned)d / PART_NODES;
        loc = atomicAdd(&lcnt[p], 1);
    }
    __syncthreads();
    if (t < 8) lbase[t] = atomicAdd(&bucketCnt[t * 16], lcnt[t]);
    __syncthreads();
    if (ok) {
        unsigned long long v = ((unsigned long long)(unsigned)s << 32) | (unsigned)d;
        bucket[(size_t)p * BCAP + lbase[p] + loc] = v;
    }
}

// phase B: scatter bucket p into col slice p (dirty lines stay on one XCD)
__global__ __launch_bounds__(256) void k_scatter(const unsigned long long* __restrict__ bucket,
                                                 const int* __restrict__ bucketCnt,
                                                 int* __restrict__ cursor,
                                                 int* __restrict__ col) {
    int p = blockIdx.x & 7;
    int cnt = bucketCnt[p * 16];
    const unsigned long long* b = bucket + (size_t)p * BCAP;
    for (int i = (blockIdx.x >> 3) * 256 + threadIdx.x; i < cnt; i += NSCAT * 256) {
        unsigned long long v = __builtin_nontemporal_load(b + i);
        int d = (int)(v & 0xffffffffu);
        int s = (int)(v >> 32);
        int pos = atomicAdd(&cursor[d], 1);
        col[d * CAP + pos] = s;
    }
}

// x (f32) -> bf16 packed, 8 elems per thread
__global__ __launch_bounds__(256) void k_cvt(const float* __restrict__ x,
                                             unsigned* __restrict__ xb) {
    int t = blockIdx.x * 256 + threadIdx.x;
    if (t >= NN * 8) return;
    const float4* p = (const float4*)(x + (size_t)t * 8);
    float4 a = p[0], b = p[1];
    uint4 o;
    o.x = bfpack2(a.x, a.y); o.y = bfpack2(a.z, a.w);
    o.z = bfpack2(b.x, b.y); o.w = bfpack2(b.z, b.w);
    ((uint4*)xb)[t] = o;
}

// W1,W2 (3 layers) -> bf16, transposed to [layer][m][col][k]
__global__ void k_prepw(const float* __restrict__ W1, const float* __restrict__ W2,
                        unsigned short* __restrict__ Wb) {
    int idx = blockIdx.x * 256 + threadIdx.x;
    if (idx >= 3 * 2 * 4096) return;
    int l = idx / 8192;
    int rem = idx - l * 8192;
    int m = rem / 4096;
    int e = rem - m * 4096;
    int c = e >> 6, k = e & 63;
    const float* W = (m == 0 ? W1 : W2) + l * 4096;
    Wb[idx] = bf16of(W[k * 64 + c]);
}

// z[i,:] = h[i,:] + sum_j h[j,:] from bf16 rows; OUTPUT bf16 (MFMA MLP input).
__global__ __launch_bounds__(256) void k_agg4(const unsigned* __restrict__ hb,
                                              const int* __restrict__ deg,
                                              const int* __restrict__ col,
                                              unsigned* __restrict__ outZb) {
    int node = blockIdx.x * 4 + (threadIdx.x >> 6);   // grid exact: 12500*4
    int lane = threadIdx.x & 63;
    int li = lane & 7;
    int slot = lane >> 3;
    int dn = deg[node];
    int base = node * CAP;
    const uint4* hb4 = (const uint4*)hb;
    float acc[8];
#pragma unroll
    for (int i = 0; i < 8; ++i) acc[i] = 0.f;

#define UNPK_ADD(U)                                                      \
    {                                                                    \
        uint4 _u = (U);                                                  \
        union { unsigned u; float f; } l0, h0, l1, h1, l2, h2, l3, h3;   \
        l0.u = _u.x << 16; h0.u = _u.x & 0xffff0000u;                    \
        l1.u = _u.y << 16; h1.u = _u.y & 0xffff0000u;                    \
        l2.u = _u.z << 16; h2.u = _u.z & 0xffff0000u;                    \
        l3.u = _u.w << 16; h3.u = _u.w & 0xffff0000u;                    \
        acc[0] += l0.f; acc[1] += h0.f; acc[2] += l1.f; acc[3] += h1.f;  \
        acc[4] += l2.f; acc[5] += h2.f; acc[6] += l3.f; acc[7] += h3.f;  \
    }

    if (slot == 0)
        UNPK_ADD(hb4[(size_t)node * 8 + li]);   // self row

    int k = slot;
    for (; k + 8 < dn; k += 16) {
        int s0 = __builtin_nontemporal_load(col + base + k);
        int s1 = __builtin_nontemporal_load(col + base + k + 8);
        uint4 u0 = hb4[(size_t)s0 * 8 + li];
        uint4 u1 = hb4[(size_t)s1 * 8 + li];
        UNPK_ADD(u0);
        UNPK_ADD(u1);
    }
    if (k < dn) {
        int s0 = __builtin_nontemporal_load(col + base + k);
        UNPK_ADD(hb4[(size_t)s0 * 8 + li]);
    }
#undef UNPK_ADD

#pragma unroll
    for (int i = 0; i < 8; ++i) acc[i] += __shfl_xor(acc[i], 8);
#pragma unroll
    for (int i = 0; i < 8; ++i) acc[i] += __shfl_xor(acc[i], 16);
#pragma unroll
    for (int i = 0; i < 8; ++i) acc[i] += __shfl_xor(acc[i], 32);

    if (slot == 0) {
        uint4 o;
        o.x = bfpack2(acc[0], acc[1]);
        o.y = bfpack2(acc[2], acc[3]);
        o.z = bfpack2(acc[4], acc[5]);
        o.w = bfpack2(acc[6], acc[7]);
        ((uint4*)outZb)[(size_t)node * 8 + li] = o;
    }
}

// MFMA MLP: Zf = relu(Zb@W1+b1)@W2+b2.  Wave = 16 rows x 64 cols.
// A-frag: lane l holds row (l&15), k = (l>>4)*8..+7 (contiguous 16B).
// B-frag: lane l holds col (l&15), same k slice -> W pre-transposed [col][k].
// C: col = lane&15, row = (lane>>4)*4 + r  [m89 verified layout].
__global__ __launch_bounds__(256) void k_mlp_mfma(const unsigned short* __restrict__ Zb,
                                                  const unsigned short* __restrict__ WbL,
                                                  const float* __restrict__ b1,
                                                  const float* __restrict__ b2,
                                                  float* __restrict__ Zf) {
    __shared__ unsigned short sm[4][16 * 72];   // padded stride 72 u16
    int w = threadIdx.x >> 6;
    int lane = threadIdx.x & 63;
    int q = lane >> 4;
    int cl = lane & 15;
    int r0 = blockIdx.x * 64 + w * 16;

    // B fragments (L2/L1-hot: shared by every wave)
    short8v B1[4][2], B2[4][2];
#pragma unroll
    for (int t = 0; t < 4; ++t) {
#pragma unroll
        for (int h = 0; h < 2; ++h) {
            B1[t][h] = *(const short8v*)(WbL + ((t * 16 + cl) * 64 + h * 32 + q * 8));
            B2[t][h] = *(const short8v*)(WbL + 4096 + ((t * 16 + cl) * 64 + h * 32 + q * 8));
        }
    }

    // A fragments from Zb row (row = r0 + cl; Zb padded past NN)
    const unsigned short* zr = Zb + (size_t)(r0 + cl) * 64;
    short8v a0 = *(const short8v*)(zr + q * 8);
    short8v a1 = *(const short8v*)(zr + 32 + q * 8);

    // GEMM1 (bias in acc init: bias depends on col only)
    float4v acc1[4];
#pragma unroll
    for (int t = 0; t < 4; ++t) {
        float b = b1[t * 16 + cl];
        acc1[t] = (float4v){b, b, b, b};
        acc1[t] = __builtin_amdgcn_mfma_f32_16x16x32_bf16(a0, B1[t][0], acc1[t], 0, 0, 0);
        acc1[t] = __builtin_amdgcn_mfma_f32_16x16x32_bf16(a1, B1[t][1], acc1[t], 0, 0, 0);
    }

    // ReLU + bf16 -> LDS [row][j] (stride 72), wave-private tile
    unsigned short* s = sm[w];
#pragma unroll
    for (int t = 0; t < 4; ++t) {
#pragma unroll
        for (int r = 0; r < 4; ++r) {
            float v = fmaxf(acc1[t][r], 0.f);
            s[(q * 4 + r) * 72 + t * 16 + cl] = bf16of(v);
        }
    }

    // A2 fragments (byte addr = cl*144 + q*16 [+64] : 16B aligned, 2-way banks)
    short8v a2_0 = *(const short8v*)(s + cl * 72 + q * 8);
    short8v a2_1 = *(const short8v*)(s + cl * 72 + 32 + q * 8);

    // GEMM2
    float4v acc2[4];
#pragma unroll
    for (int t = 0; t < 4; ++t) {
        float b = b2[t * 16 + cl];
        acc2[t] = (float4v){b, b, b, b};
        acc2[t] = __builtin_amdgcn_mfma_f32_16x16x32_bf16(a2_0, B2[t][0], acc2[t], 0, 0, 0);
        acc2[t] = __builtin_amdgcn_mfma_f32_16x16x32_bf16(a2_1, B2[t][1], acc2[t], 0, 0, 0);
    }

    // store f32 (lanes of one q write 64B contiguous per (t,r))
#pragma unroll
    for (int t = 0; t < 4; ++t) {
#pragma unroll
        for (int r = 0; r < 4; ++r) {
            int row = r0 + q * 4 + r;
            if (row < NN) Zf[(size_t)row * 64 + t * 16 + cl] = acc2[t][r];
        }
    }
}

// per-column sum & sumsq into statsL[0:64]/[64:128]
__global__ __launch_bounds__(256) void k_stats(const float* __restrict__ B,
                                               float* __restrict__ statsL) {
    __shared__ float ssum[256];
    __shared__ float sss[256];
    int t = threadIdx.x;
    int g = blockIdx.x * 256 + t;
    int c = g & 63;
    int rs = g >> 6;
    int stride = (gridDim.x * 256) >> 6;
    float sum = 0.f, ss = 0.f;
    for (int r = rs; r < NN; r += stride) {
        float v = B[(size_t)r * 64 + c];
        sum += v;
        ss = fmaf(v, v, ss);
    }
    ssum[t] = sum;
    sss[t] = ss;
    __syncthreads();
    if (t < 64) {
        float s4 = ssum[t] + ssum[t + 64] + ssum[t + 128] + ssum[t + 192];
        float q4 = sss[t] + sss[t + 64] + sss[t + 128] + sss[t + 192];
        atomicAdd(&statsL[t], s4);
        atomicAdd(&statsL[64 + t], q4);
    }
}

// BN affine (computed inline from statsL) + ReLU + bf16 pack
__global__ __launch_bounds__(256) void k_bnapply16(const float* __restrict__ Z,
                                                   const float* __restrict__ statsL,
                                                   const float* __restrict__ gammaL,
                                                   const float* __restrict__ betaL,
                                                   unsigned* __restrict__ hb) {
    __shared__ float sa[64];
    __shared__ float sc[64];
    int tt = threadIdx.x;
    if (tt < 64) {
        float mean = statsL[tt] * (1.f / NN);
        float var = statsL[64 + tt] * (1.f / NN) - mean * mean;
        float a = gammaL[tt] * rsqrtf(var + BN_EPS);
        sa[tt] = a;
        sc[tt] = fmaf(-mean, a, betaL[tt]);
    }
    __syncthreads();
    int t = blockIdx.x * 256 + tt;
    if (t >= NN * 8) return;
    int cb = (t & 7) * 8;
    const float4* p = (const float4*)(Z + (size_t)t * 8);
    float4 a = p[0], b = p[1];
    a.x = fmaxf(fmaf(a.x, sa[cb + 0], sc[cb + 0]), 0.f);
    a.y = fmaxf(fmaf(a.y, sa[cb + 1], sc[cb + 1]), 0.f);
    a.z = fmaxf(fmaf(a.z, sa[cb + 2], sc[cb + 2]), 0.f);
    a.w = fmaxf(fmaf(a.w, sa[cb + 3], sc[cb + 3]), 0.f);
    b.x = fmaxf(fmaf(b.x, sa[cb + 4], sc[cb + 4]), 0.f);
    b.y = fmaxf(fmaf(b.y, sa[cb + 5], sc[cb + 5]), 0.f);
    b.z = fmaxf(fmaf(b.z, sa[cb + 6], sc[cb + 6]), 0.f);
    b.w = fmaxf(fmaf(b.w, sa[cb + 7], sc[cb + 7]), 0.f);
    uint4 o;
    o.x = bfpack2(a.x, a.y); o.y = bfpack2(a.z, a.w);
    o.z = bfpack2(b.x, b.y); o.w = bfpack2(b.z, b.w);
    ((uint4*)hb)[t] = o;
}

// final BN apply (affine inline, no relu, f32 out)
__global__ __launch_bounds__(256) void k_apply_aff(const float* __restrict__ B,
                                                   const float* __restrict__ statsL,
                                                   const float* __restrict__ gammaL,
                                                   const float* __restrict__ betaL,
                                                   float* __restrict__ out) {
    __shared__ float sa[64];
    __shared__ float sc[64];
    int t = threadIdx.x;
    if (t < 64) {
        float mean = statsL[t] * (1.f / NN);
        float var = statsL[64 + t] * (1.f / NN) - mean * mean;
        float a = gammaL[t] * rsqrtf(var + BN_EPS);
        sa[t] = a;
        sc[t] = fmaf(-mean, a, betaL[t]);
    }
    __syncthreads();
    int i4 = blockIdx.x * 256 + t;
    if (i4 >= NN * 16) return;
    int cb = (i4 & 15) * 4;
    float4 v = ((const float4*)B)[i4];
    float4 o;
    o.x = fmaf(v.x, sa[cb + 0], sc[cb + 0]);
    o.y = fmaf(v.y, sa[cb + 1], sc[cb + 1]);
    o.z = fmaf(v.z, sa[cb + 2], sc[cb + 2]);
    o.w = fmaf(v.w, sa[cb + 3], sc[cb + 3]);
    ((float4*)out)[i4] = o;
}

extern "C" void kernel_launch(void* const* d_in, const int* in_sizes, int n_in,
                              void* d_out, int out_size, void* d_ws, size_t ws_size,
                              hipStream_t stream) {
    const float* x     = (const float*)d_in[0];
    const int*   ei    = (const int*)d_in[1];   // [2][E]
    const float* W1    = (const float*)d_in[2];
    const float* b1    = (const float*)d_in[3];
    const float* W2    = (const float*)d_in[4];
    const float* b2    = (const float*)d_in[5];
    const float* gamma = (const float*)d_in[6];
    const float* beta  = (const float*)d_in[7];
    float* out = (float*)d_out;

    const int* src = ei;        // edge_index[0]
    const int* dst = ei + EE;   // edge_index[1]

    char* w = (char*)d_ws;
    unsigned*       Zb  = (unsigned*)w;       w += (size_t)(NN + 64) * DD * 2;  // bf16 agg out (padded)
    float*          Zf  = (float*)w;          w += (size_t)NN * DD * 4;         // f32 mlp out
    unsigned*       Hb  = (unsigned*)w;       w += (size_t)NN * DD * 2;         // bf16 bn out
    unsigned*       Xb  = (unsigned*)w;       w += (size_t)NN * DD * 2;         // bf16 x
    int*            col = (int*)w;            w += (size_t)NN * CAP * 4;        // padded CSR
    unsigned long long* bucket = (unsigned long long*)w;
    w += (size_t)NPART * BCAP * 8;
    int*            cursor    = (int*)w;      w += (size_t)NN * 4;              // degree after scatter
    int*            bucketCnt = (int*)w;      w += 128 * 4;
    float*          stats     = (float*)w;    w += 384 * 4;                     // 3 layers x 128
    unsigned short* Wb        = (unsigned short*)w; w += 3 * 2 * 4096 * 2;      // bf16 W^T

    // ---- setup: zero ctrl, bucket edges (+zero cursor), cvt x, prep W, scatter ----
    k_zero_small<<<1, 512, 0, stream>>>(bucketCnt, stats);
    k_build<<<NB_BUCKET, 1024, 0, stream>>>(src, dst, bucket, bucketCnt, cursor);
    k_cvt<<<NB_ELT8, 256, 0, stream>>>(x, Xb);
    k_prepw<<<96, 256, 0, stream>>>(W1, W2, Wb);
    k_scatter<<<NPART * NSCAT, 256, 0, stream>>>(bucket, bucketCnt, cursor, col);

    // ---- layer 0 ----
    k_agg4<<<NB_AGG, 256, 0, stream>>>(Xb, cursor, col, Zb);
    k_mlp_mfma<<<NB_MLP, 256, 0, stream>>>((unsigned short*)Zb, Wb, b1, b2, Zf);
    k_stats<<<256, 256, 0, stream>>>(Zf, stats);
    k_bnapply16<<<NB_ELT8, 256, 0, stream>>>(Zf, stats, gamma, beta, Hb);

    // ---- layer 1 ----
    k_agg4<<<NB_AGG, 256, 0, stream>>>(Hb, cursor, col, Zb);
    k_mlp_mfma<<<NB_MLP, 256, 0, stream>>>((unsigned short*)Zb, Wb + 8192, b1 + 64, b2 + 64, Zf);
    k_stats<<<256, 256, 0, stream>>>(Zf, stats + 128);
    k_bnapply16<<<NB_ELT8, 256, 0, stream>>>(Zf, stats + 128, gamma + 64, beta + 64, Hb);

    // ---- layer 2 ----
    k_agg4<<<NB_AGG, 256, 0, stream>>>(Hb, cursor, col, Zb);
    k_mlp_mfma<<<NB_MLP, 256, 0, stream>>>((unsigned short*)Zb, Wb + 16384, b1 + 128, b2 + 128, Zf);
    k_stats<<<256, 256, 0, stream>>>(Zf, stats + 256);
    k_apply_aff<<<NB_APPLY, 256, 0, stream>>>(Zf, stats + 256, gamma + 128, beta + 128, out);
}